// Round 17
// baseline (799.391 us; speedup 1.0000x reference)
//
#include <hip/hip_runtime.h>

#define SEQ     4096
#define BATCH   2
#define NROWS   8192        // BATCH*SEQ
#define HID     2048
#define INTER_  4096
#define NHEADS  32
#define HDIM    128
#define NSTATE  128
#define CDIM    4352        // INTER + 2*STATE
#define NPROJ_  8480        // INTER + CDIM + HEADS
#define NPAD    8704        // NPROJ_ padded (zero-filled W1 rows)
#define NCH     16          // SEQ / 256
#define CHUNK_  256

typedef __attribute__((ext_vector_type(8))) short bf16x8;
typedef __attribute__((ext_vector_type(4))) short short4v;
typedef __attribute__((ext_vector_type(4))) float f32x4;

#define AS1 __attribute__((address_space(1)))
#define AS3 __attribute__((address_space(3)))

__device__ __forceinline__ float bf2f(short s) {
  union { unsigned u; float f; } x;
  x.u = ((unsigned)(unsigned short)s) << 16;
  return x.f;
}
__device__ __forceinline__ short f2bf(float f) {
  union { float f; unsigned u; } x; x.f = f;
  unsigned r = x.u + 0x7FFFu + ((x.u >> 16) & 1u);
  return (short)(r >> 16);
}

// ---------------- f32 -> bf16 conversion, 4 elems/thread; zero-pad past nsrc4 ----------------
__global__ void cvt_bf16(const float* __restrict__ in, short* __restrict__ out,
                         int n4, int nsrc4) {
  int i = blockIdx.x * 256 + threadIdx.x;
  if (i >= n4) return;
  short4v o = {0, 0, 0, 0};
  if (i < nsrc4) {
    f32x4 v = *(const f32x4*)(in + (size_t)i * 4);
    o = (short4v){ f2bf(v.x), f2bf(v.y), f2bf(v.z), f2bf(v.w) };
  }
  *(short4v*)(out + (size_t)i * 4) = o;
}

// =============== 256x256 bf16 GEMM, 8 waves, BK=64, free-running halves (r8/r15 BEST) ======
// C = A(MxK) @ Bw(NpadxK)^T.  MODE 0: f32 out.  MODE 1: in_proj split epilogue.
// dt NOT fused (r14/r15 A/B: fat epilogue costs ~90us of K-loop codegen perturbation).
template<int MODE>
__global__ __launch_bounds__(512, 1)
void gemm256(const short* __restrict__ A, const short* __restrict__ Bw,
             int M, int N, int K, int nM,
             float* __restrict__ outF, short* __restrict__ gate,
             short* __restrict__ hbc, float* __restrict__ dtraw)
{
  __shared__ __align__(16) short lds[2][2][2][256 * 32];   // [buf][mat][khalf]
  const int tid = threadIdx.x;
  const int lane = tid & 63, wave = tid >> 6;
  const int l16 = lane & 15, lhi = lane >> 4;
  const int wm = wave >> 2, wn = wave & 3;      // 2M x 4N; wave tile 128x64

  const int bm = blockIdx.x % nM, bn = blockIdx.x / nM;   // bm-fast
  const size_t row0 = (size_t)bm * 256;
  const int    col0 = bn * 256;

  const short* Ab  = A + row0 * K;
  const short* Bbp = Bw + (size_t)col0 * K;

  f32x4 acc[8][4];
  #pragma unroll
  for (int m = 0; m < 8; ++m)
    #pragma unroll
    for (int n = 0; n < 4; ++n) acc[m][n] = (f32x4){0.f, 0.f, 0.f, 0.f};

  auto stage = [&](int bufq, int mat, int kh, int ko) {
    const short* gsrc = mat ? Bbp : Ab;
    short* base = &lds[bufq][mat][kh][0];
    #pragma unroll
    for (int j = 0; j < 2; ++j) {
      int u = j * 512 + tid;
      int r = u >> 2;
      int g = (u & 3) ^ ((r >> 1) & 3);
      __builtin_amdgcn_global_load_lds(
          (const AS1 unsigned*)(gsrc + (size_t)r * K + ko + kh * 32 + g * 8),
          (AS3 unsigned*)(base + (j * 512 + wave * 64) * 8), 16, 0, 0);
    }
  };
  auto readA = [&](int bufq, int kh, int mh, bf16x8* a) {
    const short* base = &lds[bufq][0][kh][0];
    #pragma unroll
    for (int f = 0; f < 4; ++f) {
      int rr = wm * 128 + mh * 64 + f * 16 + l16;
      int g = lhi ^ ((rr >> 1) & 3);
      a[f] = *(const bf16x8*)(base + rr * 32 + g * 8);
    }
  };
  auto readB = [&](int bufq, int kh, bf16x8* b) {
    const short* base = &lds[bufq][1][kh][0];
    #pragma unroll
    for (int f = 0; f < 4; ++f) {
      int rr = wn * 64 + f * 16 + l16;
      int g = lhi ^ ((rr >> 1) & 3);
      b[f] = *(const bf16x8*)(base + rr * 32 + g * 8);
    }
  };

  const int nt = K / 64;              // 32 (gemm1) / 64 (gemm2)
  stage(0, 0, 0, 0); stage(0, 1, 0, 0); stage(0, 0, 1, 0); stage(0, 1, 1, 0);
  asm volatile("s_waitcnt vmcnt(4)" ::: "memory");
  __builtin_amdgcn_s_barrier();

  for (int t = 0; t < nt; ++t) {
    const int buf = t & 1, nb = buf ^ 1;
    const int kon = (t + 1) * 64;
    const bool pf = (t + 1 < nt);

    #pragma unroll
    for (int kh = 0; kh < 2; ++kh) {
      if (pf) { stage(nb, 0, kh, kon); stage(nb, 1, kh, kon); }
      bf16x8 a[8], b[4];
      readA(buf, kh, 0, a); readA(buf, kh, 1, a + 4); readB(buf, kh, b);
      __builtin_amdgcn_s_setprio(1);
      #pragma unroll
      for (int mf = 0; mf < 8; ++mf)
        #pragma unroll
        for (int nf = 0; nf < 4; ++nf)
          acc[mf][nf] = __builtin_amdgcn_mfma_f32_16x16x32_bf16(a[mf], b[nf], acc[mf][nf], 0, 0, 0);
      __builtin_amdgcn_s_setprio(0);
      if (pf || kh == 0) {
        if (pf) asm volatile("s_waitcnt vmcnt(4)" ::: "memory");
        else    asm volatile("s_waitcnt vmcnt(0)" ::: "memory");
        __builtin_amdgcn_s_barrier();
      }
    }
  }

  #pragma unroll
  for (int mh = 0; mh < 2; ++mh) {
    #pragma unroll
    for (int f = 0; f < 4; ++f) {
      #pragma unroll
      for (int nf = 0; nf < 4; ++nf) {
        #pragma unroll
        for (int jq = 0; jq < 4; ++jq) {
          int gr = (int)row0 + wm * 128 + mh * 64 + f * 16 + lhi * 4 + jq;
          int gc = col0 + wn * 64 + nf * 16 + l16;
          float v = acc[mh * 4 + f][nf][jq];
          if (MODE == 0) {
            outF[(size_t)gr * N + gc] = v;
          } else {
            if (gc < INTER_)             gate[(size_t)gr * INTER_ + gc] = f2bf(v);
            else if (gc < INTER_ + CDIM) hbc[(size_t)gr * CDIM + (gc - INTER_)] = f2bf(v);
            else if (gc < NPROJ_)        dtraw[(size_t)gr * NHEADS + (gc - INTER_ - CDIM)] = v;
          }
        }
      }
    }
  }
}

// ---------------- depthwise causal conv (K=4) + silu, VECTORIZED (16B/lane) ----------------
__global__ __launch_bounds__(256)
void conv_t(const short* __restrict__ hbc, const float* __restrict__ cw,
            const float* __restrict__ cb, short* __restrict__ xsT,
            short* __restrict__ Bb, short* __restrict__ Cb, short* __restrict__ BbT)
{
  __shared__ short sOut[64][132];
  int ct = blockIdx.y;
  int t = threadIdx.x;
  int cg = (t & 15) * 8;              // channel offset within 128
  int rg = (t >> 4) * 4;              // row offset within 64
  int c0 = ct * 128 + cg;
  int row0 = blockIdx.x * 64;
  int s0 = row0 & (SEQ - 1);

  float w[4][8], bias[8];
  #pragma unroll
  for (int ch = 0; ch < 8; ++ch) {
    f32x4 wv = *(const f32x4*)(cw + (size_t)(c0 + ch) * 4);
    w[0][ch] = wv.x; w[1][ch] = wv.y; w[2][ch] = wv.z; w[3][ch] = wv.w;
    bias[ch] = cb[c0 + ch];
  }
  float in[7][8];
  #pragma unroll
  for (int j = 0; j < 7; ++j) {
    int sp = s0 + rg + j - 3;
    if (sp >= 0) {
      bf16x8 v = *(const bf16x8*)(hbc + (size_t)(row0 + rg + j - 3) * CDIM + c0);
      #pragma unroll
      for (int ch = 0; ch < 8; ++ch) in[j][ch] = bf2f(v[ch]);
    } else {
      #pragma unroll
      for (int ch = 0; ch < 8; ++ch) in[j][ch] = 0.f;
    }
  }
  #pragma unroll
  for (int r = 0; r < 4; ++r) {
    bf16x8 o;
    #pragma unroll
    for (int ch = 0; ch < 8; ++ch) {
      float a = bias[ch] + w[0][ch] * in[r][ch] + w[1][ch] * in[r + 1][ch]
                         + w[2][ch] * in[r + 2][ch] + w[3][ch] * in[r + 3][ch];
      float v = a / (1.f + expf(-a));
      o[ch] = f2bf(v);
    }
    if (ct < 33) {
      *(short4v*)(&sOut[rg + r][cg])     = (short4v){o[0], o[1], o[2], o[3]};
      *(short4v*)(&sOut[rg + r][cg + 4]) = (short4v){o[4], o[5], o[6], o[7]};
    }
    if (ct == 32)      *(bf16x8*)(Bb + (size_t)(row0 + rg + r) * NSTATE + cg) = o;
    else if (ct == 33) *(bf16x8*)(Cb + (size_t)(row0 + rg + r) * NSTATE + cg) = o;
  }
  if (ct >= 33) return;
  __syncthreads();
  int p = t >> 1, sh = (t & 1) * 32;
  int b = row0 >> 12;
  size_t dst;
  short* outp;
  if (ct < 32) { outp = xsT; dst = ((size_t)(b * 32 + ct) * 128 + p) * SEQ + s0 + sh; }
  else         { outp = BbT; dst = ((size_t)b * 128 + p) * SEQ + s0 + sh; }
  #pragma unroll
  for (int g = 0; g < 8; ++g) {
    short4v o;
    o[0] = sOut[sh + g * 4 + 0][p];
    o[1] = sOut[sh + g * 4 + 1][p];
    o[2] = sOut[sh + g * 4 + 2][p];
    o[3] = sOut[sh + g * 4 + 3][p];
    *(short4v*)(outp + dst + g * 4) = o;
  }
}

// ---------------- dt = clip(softplus(dt_raw + bias), 0, 100) -> transposed dtT[h][row] ----
__global__ void dt_proc(const float* __restrict__ dtraw, const float* __restrict__ dtb,
                        float* __restrict__ dtT, int n) {
  int i = blockIdx.x * 256 + threadIdx.x;
  if (i >= n) return;
  float x = dtraw[i] + dtb[i & (NHEADS - 1)];
  float sp = (x > 20.f) ? x : log1pf(expf(x));
  float d = fminf(fmaxf(sp, 0.f), 100.f);
  int row = i >> 5, h = i & 31;
  dtT[(size_t)h * NROWS + row] = d;
}

// ---------------- chunk state (MFMA): S^T[p][n], bf16 out via LDS relayout ----------------
__global__ __launch_bounds__(256)
void ssm_state(const short* __restrict__ xsT, const short* __restrict__ BbT,
               const float* __restrict__ dtT, const float* __restrict__ Alog,
               short* __restrict__ csb, float* __restrict__ dAsum)
{
  int blk = blockIdx.x;                       // (b*16+cc)*32+h
  int h = blk & 31, cc = (blk >> 5) & 15, b = blk >> 9;
  int tid = threadIdx.x, lane = tid & 63, wave = tid >> 6;
  int l16 = lane & 15, lhi = lane >> 4;
  int s0 = cc * CHUNK_;

  __shared__ float acum[256];
  __shared__ float sdt[256];
  __shared__ float wsum[4];
  __shared__ __align__(16) short sY[128 * 132];   // output relayout buffer
  { float Ah = -expf(Alog[h]);
    float d = dtT[(size_t)h * NROWS + (size_t)b * SEQ + s0 + tid];
    sdt[tid] = d;
    float v = Ah * d;
    #pragma unroll
    for (int off = 1; off < 64; off <<= 1) {
      float t = __shfl_up(v, off, 64);
      if (lane >= off) v += t;
    }
    if (lane == 63) wsum[wave] = v;
    __syncthreads();
    float addv = 0.f;
    #pragma unroll
    for (int w = 0; w < 3; ++w) if (w < wave) addv += wsum[w];
    acum[tid] = v + addv;
  }
  __syncthreads();
  float alast = acum[255];

  const short* xbase = xsT + ((size_t)(b * 32 + h) * 128) * SEQ + s0;
  const short* bbase = BbT + ((size_t)b * 128) * SEQ + s0;

  f32x4 acc[2][8];
  #pragma unroll
  for (int m = 0; m < 2; ++m)
    #pragma unroll
    for (int n = 0; n < 8; ++n) acc[m][n] = (f32x4){0.f, 0.f, 0.f, 0.f};

  for (int lt0 = 0; lt0 < 256; lt0 += 32) {
    float fe[8];
    #pragma unroll
    for (int e = 0; e < 8; ++e) {
      int kl = lt0 + lhi * 8 + e;
      fe[e] = sdt[kl] * __expf(alast - acum[kl]);
    }
    bf16x8 af[2];
    #pragma unroll
    for (int m = 0; m < 2; ++m) {
      bf16x8 raw = *(const bf16x8*)(xbase + (size_t)(wave * 32 + m * 16 + l16) * SEQ + lt0 + lhi * 8);
      bf16x8 sc;
      #pragma unroll
      for (int e = 0; e < 8; ++e) sc[e] = f2bf(bf2f(raw[e]) * fe[e]);
      af[m] = sc;
    }
    #pragma unroll
    for (int n = 0; n < 8; ++n) {
      bf16x8 bfv = *(const bf16x8*)(bbase + (size_t)(n * 16 + l16) * SEQ + lt0 + lhi * 8);
      acc[0][n] = __builtin_amdgcn_mfma_f32_16x16x32_bf16(af[0], bfv, acc[0][n], 0, 0, 0);
      acc[1][n] = __builtin_amdgcn_mfma_f32_16x16x32_bf16(af[1], bfv, acc[1][n], 0, 0, 0);
    }
  }
  // relayout through LDS (conflict-free: lhi step 264 dwords = 8 mod 32) -> coalesced store
  #pragma unroll
  for (int m = 0; m < 2; ++m)
    #pragma unroll
    for (int n = 0; n < 8; ++n)
      #pragma unroll
      for (int j = 0; j < 4; ++j) {
        int p = wave * 32 + m * 16 + lhi * 4 + j;
        int ng = n * 16 + l16;
        sY[p * 132 + ng] = f2bf(acc[m][n][j]);
      }
  __syncthreads();
  size_t base = (size_t)blk * 16384;
  { int p = tid >> 1, seg = (tid & 1) * 64;      // 2 lanes/row, 128B contiguous each
    #pragma unroll
    for (int k = 0; k < 16; ++k) {
      short4v v = *(const short4v*)(&sY[p * 132 + seg + k * 4]);
      *(short4v*)(csb + base + (size_t)p * NSTATE + seg + k * 4) = v;
    }
  }
  if (tid == 0) dAsum[blk] = alast;
}

// ---------------- inter-chunk sequential scan (IN-PLACE bf16, 2 elems/thread) ----------------
__global__ void ssm_scan(short* __restrict__ csb, const float* __restrict__ dAsum) {
  int idx = blockIdx.x * 256 + threadIdx.x;   // over BATCH*HEADS*8192 pairs
  int np2 = idx & 8191;
  int bh = idx >> 13;
  int h = bh & 31, b = bh >> 5;
  float r0 = 0.f, r1 = 0.f;
  #pragma unroll
  for (int c = 0; c < NCH; ++c) {
    size_t base = ((size_t)((b * NCH + c) * NHEADS + h)) * 16384 + (size_t)np2 * 2;
    short* ptr = csb + base;
    short v0 = ptr[0], v1 = ptr[1];
    float f0 = bf2f(v0), f1 = bf2f(v1);
    ptr[0] = f2bf(r0); ptr[1] = f2bf(r1);
    float e = __expf(dAsum[(b * NCH + c) * NHEADS + h]);
    r0 = r0 * e + f0;
    r1 = r1 * e + f1;
  }
}

// ---------------- Y (MFMA): Y = M' @ xdt + exp(acum)*(C @ S_prev^T), gate in-place ----
__global__ __launch_bounds__(256)
void ssm_y(const short* __restrict__ xsT, const short* __restrict__ Bb,
           const short* __restrict__ Cb, const float* __restrict__ dtT,
           const float* __restrict__ Alog, const float* __restrict__ Dv,
           const short* __restrict__ csb, short* __restrict__ gateY)
{
  int blk = blockIdx.y, lt = blockIdx.x;
  int h = blk & 31, cc = (blk >> 5) & 15, b = blk >> 9;
  int tid = threadIdx.x, lane = tid & 63, wave = tid >> 6;
  int l16 = lane & 15, lhi = lane >> 4;
  int s0 = cc * CHUNK_;
  size_t row0 = (size_t)b * SEQ + s0;

  __shared__ float acum[256];
  __shared__ float sdt[256];
  __shared__ float wsum[4];
  __shared__ __align__(16) short M_lds[64 * 264];

  { float Ah = -expf(Alog[h]);
    float d = dtT[(size_t)h * NROWS + row0 + tid];
    sdt[tid] = d;
    float v = Ah * d;
    #pragma unroll
    for (int off = 1; off < 64; off <<= 1) {
      float t = __shfl_up(v, off, 64);
      if (lane >= off) v += t;
    }
    if (lane == 63) wsum[wave] = v;
    __syncthreads();
    float addv = 0.f;
    #pragma unroll
    for (int w = 0; w < 3; ++w) if (w < wave) addv += wsum[w];
    acum[tid] = v + addv;
  }
  __syncthreads();

  float Dh = Dv[h];

  // ---- phase 1: G = C_l · B^T, decay+mask(+D/dt diag) -> M_lds bf16 (wave > lt skipped)
  if (wave <= lt) {
    f32x4 acc1[4][4];
    #pragma unroll
    for (int m = 0; m < 4; ++m)
      #pragma unroll
      for (int n = 0; n < 4; ++n) acc1[m][n] = (f32x4){0.f, 0.f, 0.f, 0.f};
    for (int kk = 0; kk < NSTATE; kk += 32) {
      bf16x8 af[4], bv[4];
      #pragma unroll
      for (int m = 0; m < 4; ++m)
        af[m] = *(const bf16x8*)(Cb + (row0 + lt * 64 + m * 16 + l16) * NSTATE + kk + lhi * 8);
      #pragma unroll
      for (int n = 0; n < 4; ++n)
        bv[n] = *(const bf16x8*)(Bb + (row0 + wave * 64 + n * 16 + l16) * NSTATE + kk + lhi * 8);
      #pragma unroll
      for (int m = 0; m < 4; ++m)
        #pragma unroll
        for (int n = 0; n < 4; ++n)
          acc1[m][n] = __builtin_amdgcn_mfma_f32_16x16x32_bf16(af[m], bv[n], acc1[m][n], 0, 0, 0);
    }
    float as_[4]; int sg_[4];
    #pragma unroll
    for (int n = 0; n < 4; ++n) { sg_[n] = wave * 64 + n * 16 + l16; as_[n] = acum[sg_[n]]; }
    #pragma unroll
    for (int m = 0; m < 4; ++m) {
      #pragma unroll
      for (int j = 0; j < 4; ++j) {
        int ll = m * 16 + lhi * 4 + j;
        int lg = lt * 64 + ll;
        float al = acum[lg];
        float dinv = Dh / fmaxf(sdt[lg], 1e-20f);
        #pragma unroll
        for (int n = 0; n < 4; ++n) {
          float v = 0.f;
          if (sg_[n] <= lg) {
            v = acc1[m][n][j] * __expf(al - as_[n]);
            if (sg_[n] == lg) v += dinv;
          }
          M_lds[ll * 264 + wave * 64 + n * 16 + l16] = f2bf(v);
        }
      }
    }
  }
  __syncthreads();

  const short* xbase = xsT + ((size_t)(b * 32 + h) * 128) * SEQ + s0;

  // ---- phase 2: Y_diag = M' @ xdt  (xdt^T frags direct from xsT global)
  f32x4 accY[4][2];
  #pragma unroll
  for (int m = 0; m < 4; ++m) { accY[m][0] = (f32x4){0,0,0,0}; accY[m][1] = (f32x4){0,0,0,0}; }
  int smax = (lt + 1) * 64;
  for (int st = 0; st < smax; st += 32) {
    float fe[8];
    #pragma unroll
    for (int e = 0; e < 8; ++e) fe[e] = sdt[st + lhi * 8 + e];
    bf16x8 bv2[2];
    #pragma unroll
    for (int n = 0; n < 2; ++n) {
      bf16x8 raw = *(const bf16x8*)(xbase + (size_t)(wave * 32 + n * 16 + l16) * SEQ + st + lhi * 8);
      bf16x8 sc;
      #pragma unroll
      for (int e = 0; e < 8; ++e) sc[e] = f2bf(bf2f(raw[e]) * fe[e]);
      bv2[n] = sc;
    }
    #pragma unroll
    for (int m = 0; m < 4; ++m) {
      bf16x8 a = *(const bf16x8*)(M_lds + (m * 16 + l16) * 264 + st + lhi * 8);
      accY[m][0] = __builtin_amdgcn_mfma_f32_16x16x32_bf16(a, bv2[0], accY[m][0], 0, 0, 0);
      accY[m][1] = __builtin_amdgcn_mfma_f32_16x16x32_bf16(a, bv2[1], accY[m][1], 0, 0, 0);
    }
  }

  // ---- phase 3: Y_off = C @ S_prev^T (bf16 S^T frags direct from global)
  f32x4 accO[4][2];
  #pragma unroll
  for (int m = 0; m < 4; ++m) { accO[m][0] = (f32x4){0,0,0,0}; accO[m][1] = (f32x4){0,0,0,0}; }
  const short* sbase = csb + (size_t)blk * 16384;
  for (int nt = 0; nt < NSTATE; nt += 32) {
    bf16x8 bv2[2];
    #pragma unroll
    for (int n = 0; n < 2; ++n) {
      int p = wave * 32 + n * 16 + l16;
      bv2[n] = *(const bf16x8*)(sbase + (size_t)p * NSTATE + nt + lhi * 8);
    }
    #pragma unroll
    for (int m = 0; m < 4; ++m) {
      bf16x8 a = *(const bf16x8*)(Cb + (row0 + lt * 64 + m * 16 + l16) * NSTATE + nt + lhi * 8);
      accO[m][0] = __builtin_amdgcn_mfma_f32_16x16x32_bf16(a, bv2[0], accO[m][0], 0, 0, 0);
      accO[m][1] = __builtin_amdgcn_mfma_f32_16x16x32_bf16(a, bv2[1], accO[m][1], 0, 0, 0);
    }
  }

  // ---- epilogue: relayout Y through LDS (M_lds free after phase 2; barrier-protected),
  //      then gate+rewrite gateY with 64B-contiguous runs (4 threads/row x 32 shorts).
  __syncthreads();                       // all waves done reading M_lds in phase 2
  #pragma unroll
  for (int m = 0; m < 4; ++m) {
    #pragma unroll
    for (int j = 0; j < 4; ++j) {
      int ll = m * 16 + lhi * 4 + j;
      float e = __expf(acum[lt * 64 + ll]);
      #pragma unroll
      for (int n = 0; n < 2; ++n) {
        int p = wave * 32 + n * 16 + l16;
        M_lds[ll * 132 + p] = f2bf(accY[m][n][j] + e * accO[m][n][j]);
      }
    }
  }
  __syncthreads();
  { int r = tid >> 2, seg = tid & 3;
    size_t row = row0 + lt * 64 + r;
    size_t adr = row * INTER_ + h * HDIM + seg * 32;
    #pragma unroll
    for (int k = 0; k < 4; ++k) {
      bf16x8 gv8 = *(const bf16x8*)(gateY + adr + k * 8);
      short4v ylo = *(const short4v*)(&M_lds[r * 132 + seg * 32 + k * 8]);
      short4v yhi = *(const short4v*)(&M_lds[r * 132 + seg * 32 + k * 8 + 4]);
      bf16x8 o;
      #pragma unroll
      for (int q = 0; q < 8; ++q) {
        float y = bf2f(q < 4 ? ylo[q] : yhi[q - 4]);
        float g = bf2f(gv8[q]);
        o[q] = f2bf(y * g / (1.f + expf(-g)));
      }
      *(bf16x8*)(gateY + adr + k * 8) = o;
    }
  }
}

// ---------------- RMSNorm in-place on bf16 gated y (vectorized 16-elem/thread) ----------------
__global__ __launch_bounds__(256)
void gate_norm(short* __restrict__ ybf, const float* __restrict__ nw)
{
  int row = blockIdx.x;
  int tid = threadIdx.x;
  size_t base = (size_t)row * INTER_ + (size_t)tid * 16;
  bf16x8 v0 = *(const bf16x8*)(ybf + base);
  bf16x8 v1 = *(const bf16x8*)(ybf + base + 8);
  float vals[16];
  float ss = 0.f;
  #pragma unroll
  for (int i = 0; i < 8; ++i) {
    vals[i] = bf2f(v0[i]); vals[8 + i] = bf2f(v1[i]);
  }
  #pragma unroll
  for (int i = 0; i < 16; ++i) ss += vals[i] * vals[i];
  #pragma unroll
  for (int off = 32; off > 0; off >>= 1) ss += __shfl_down(ss, off);
  __shared__ float ws4[4];
  if ((tid & 63) == 0) ws4[tid >> 6] = ss;
  __syncthreads();
  float tot = ws4[0] + ws4[1] + ws4[2] + ws4[3];
  float scale = rsqrtf(tot * (1.f / 4096.f) + 1e-5f);
  bf16x8 o0, o1;
  #pragma unroll
  for (int i = 0; i < 8; ++i) {
    o0[i] = f2bf(vals[i] * scale * nw[tid * 16 + i]);
    o1[i] = f2bf(vals[8 + i] * scale * nw[tid * 16 + 8 + i]);
  }
  *(bf16x8*)(ybf + base) = o0;
  *(bf16x8*)(ybf + base + 8) = o1;
}

// ---------------- launch ----------------
extern "C" void kernel_launch(void* const* d_in, const int* in_sizes, int n_in,
                              void* d_out, int out_size, void* d_ws, size_t ws_size,
                              hipStream_t stream)
{
  const float* Xf   = (const float*)d_in[0];
  const float* W1f  = (const float*)d_in[1];
  const float* cw   = (const float*)d_in[2];
  const float* cb   = (const float*)d_in[3];
  const float* Alog = (const float*)d_in[4];
  const float* dtb  = (const float*)d_in[5];
  const float* Dv   = (const float*)d_in[6];
  const float* nw   = (const float*)d_in[7];
  const float* W2f  = (const float*)d_in[8];
  float* outp = (float*)d_out;
  char* ws = (char*)d_ws;

  // ---- workspace layout: ~232.8 MB (lifetime-aliased), exact r15 ----
  size_t off = 0;
  short* Xb  = (short*)(ws + off); off += (size_t)NROWS * HID * 2;      // 33.55 MB
  short* W1b = (short*)(ws + off); off += (size_t)NPAD * HID * 2;       // 35.65 MB (zero-padded)
  short* xsT = (short*)ws;   // alias over Xb+W1b (dead after gemm1): 67.1 <= 69.2 MB
  short* W2b = (short*)(ws + off); off += (size_t)HID * INTER_ * 2;     // 16.78 MB
  short* gateY = (short*)(ws + off); off += (size_t)NROWS * INTER_ * 2; // 67.11 MB
  short* hbc  = (short*)(ws + off); off += (size_t)NROWS * CDIM * 2;    // 71.30 MB
  float* dtv  = (float*)(ws + off); off += (size_t)NROWS * NHEADS * 4;  // 1.05 MB
  float* dtT  = (float*)(ws + off); off += (size_t)NROWS * NHEADS * 4;  // 1.05 MB
  short* Bb   = (short*)(ws + off); off += (size_t)NROWS * NSTATE * 2;  // 2.10 MB
  short* Cb   = (short*)(ws + off); off += (size_t)NROWS * NSTATE * 2;  // 2.10 MB
  short* BbT  = (short*)(ws + off); off += (size_t)NROWS * NSTATE * 2;  // 2.10 MB
  float* dAs  = (float*)(ws + off); off += 4096;
  short* csb  = (short*)hbc;  // alias over hbc (dead after conv): 33.5 <= 71.3 MB

  cvt_bf16<<<(NROWS * HID / 4 + 255) / 256, 256, 0, stream>>>(
      Xf, Xb, NROWS * HID / 4, NROWS * HID / 4);
  cvt_bf16<<<(NPAD * HID / 4 + 255) / 256, 256, 0, stream>>>(
      W1f, W1b, NPAD * HID / 4, NPROJ_ * HID / 4);
  cvt_bf16<<<(HID * INTER_ / 4 + 255) / 256, 256, 0, stream>>>(
      W2f, W2b, HID * INTER_ / 4, HID * INTER_ / 4);

  // gemm1: 32 row tiles x 34 col tiles; bm fast
  gemm256<1><<<(NROWS / 256) * (NPAD / 256), 512, 0, stream>>>(
      Xb, W1b, NROWS, NPROJ_, HID, NROWS / 256, nullptr, gateY, hbc, dtv);

  dt_proc<<<(NROWS * NHEADS) / 256, 256, 0, stream>>>(dtv, dtb, dtT, NROWS * NHEADS);
  conv_t<<<dim3(NROWS / 64, 34), 256, 0, stream>>>(hbc, cw, cb, xsT, Bb, Cb, BbT);

  ssm_state<<<BATCH * NCH * NHEADS, 256, 0, stream>>>(xsT, BbT, dtT, Alog, csb, dAs);
  ssm_scan<<<(BATCH * NHEADS * 8192) / 256, 256, 0, stream>>>(csb, dAs);
  ssm_y<<<dim3(4, BATCH * NCH * NHEADS), 256, 0, stream>>>(xsT, Bb, Cb, dtT, Alog, Dv, csb, gateY);

  gate_norm<<<NROWS, 256, 0, stream>>>(gateY, nw);

  // gemm2: 32 row tiles x 8 col tiles
  gemm256<0><<<(NROWS / 256) * (HID / 256), 512, 0, stream>>>(
      gateY, W2b, NROWS, HID, INTER_, NROWS / 256, outp, nullptr, nullptr, nullptr);
}

// Round 18
// 791.102 us; speedup vs baseline: 1.0105x; 1.0105x over previous
//
#include <hip/hip_runtime.h>

#define SEQ     4096
#define BATCH   2
#define NROWS   8192        // BATCH*SEQ
#define HID     2048
#define INTER_  4096
#define NHEADS  32
#define HDIM    128
#define NSTATE  128
#define CDIM    4352        // INTER + 2*STATE
#define NPROJ_  8480        // INTER + CDIM + HEADS
#define NPAD    8704        // NPROJ_ padded (zero-filled W1 rows)
#define NCH     16          // SEQ / 256
#define CHUNK_  256

typedef __attribute__((ext_vector_type(8))) short bf16x8;
typedef __attribute__((ext_vector_type(4))) short short4v;
typedef __attribute__((ext_vector_type(4))) float f32x4;

#define AS1 __attribute__((address_space(1)))
#define AS3 __attribute__((address_space(3)))

__device__ __forceinline__ float bf2f(short s) {
  union { unsigned u; float f; } x;
  x.u = ((unsigned)(unsigned short)s) << 16;
  return x.f;
}
__device__ __forceinline__ short f2bf(float f) {
  union { float f; unsigned u; } x; x.f = f;
  unsigned r = x.u + 0x7FFFu + ((x.u >> 16) & 1u);
  return (short)(r >> 16);
}

// ---------------- f32 -> bf16 conversion, 4 elems/thread; zero-pad past nsrc4 ----------------
__global__ void cvt_bf16(const float* __restrict__ in, short* __restrict__ out,
                         int n4, int nsrc4) {
  int i = blockIdx.x * 256 + threadIdx.x;
  if (i >= n4) return;
  short4v o = {0, 0, 0, 0};
  if (i < nsrc4) {
    f32x4 v = *(const f32x4*)(in + (size_t)i * 4);
    o = (short4v){ f2bf(v.x), f2bf(v.y), f2bf(v.z), f2bf(v.w) };
  }
  *(short4v*)(out + (size_t)i * 4) = o;
}

// =============== 256x256 bf16 GEMM, 8 waves, BK=64, free-running halves (r8/r15 BEST) ======
// C = A(MxK) @ Bw(NpadxK)^T.  MODE 0: f32 out.  MODE 1: in_proj split epilogue.
// dt NOT fused (r14/r15 A/B: fat epilogue costs ~90us of K-loop codegen perturbation).
template<int MODE>
__global__ __launch_bounds__(512, 1)
void gemm256(const short* __restrict__ A, const short* __restrict__ Bw,
             int M, int N, int K, int nM,
             float* __restrict__ outF, short* __restrict__ gate,
             short* __restrict__ hbc, float* __restrict__ dtraw)
{
  __shared__ __align__(16) short lds[2][2][2][256 * 32];   // [buf][mat][khalf]
  const int tid = threadIdx.x;
  const int lane = tid & 63, wave = tid >> 6;
  const int l16 = lane & 15, lhi = lane >> 4;
  const int wm = wave >> 2, wn = wave & 3;      // 2M x 4N; wave tile 128x64

  const int bm = blockIdx.x % nM, bn = blockIdx.x / nM;   // bm-fast
  const size_t row0 = (size_t)bm * 256;
  const int    col0 = bn * 256;

  const short* Ab  = A + row0 * K;
  const short* Bbp = Bw + (size_t)col0 * K;

  f32x4 acc[8][4];
  #pragma unroll
  for (int m = 0; m < 8; ++m)
    #pragma unroll
    for (int n = 0; n < 4; ++n) acc[m][n] = (f32x4){0.f, 0.f, 0.f, 0.f};

  auto stage = [&](int bufq, int mat, int kh, int ko) {
    const short* gsrc = mat ? Bbp : Ab;
    short* base = &lds[bufq][mat][kh][0];
    #pragma unroll
    for (int j = 0; j < 2; ++j) {
      int u = j * 512 + tid;
      int r = u >> 2;
      int g = (u & 3) ^ ((r >> 1) & 3);
      __builtin_amdgcn_global_load_lds(
          (const AS1 unsigned*)(gsrc + (size_t)r * K + ko + kh * 32 + g * 8),
          (AS3 unsigned*)(base + (j * 512 + wave * 64) * 8), 16, 0, 0);
    }
  };
  auto readA = [&](int bufq, int kh, int mh, bf16x8* a) {
    const short* base = &lds[bufq][0][kh][0];
    #pragma unroll
    for (int f = 0; f < 4; ++f) {
      int rr = wm * 128 + mh * 64 + f * 16 + l16;
      int g = lhi ^ ((rr >> 1) & 3);
      a[f] = *(const bf16x8*)(base + rr * 32 + g * 8);
    }
  };
  auto readB = [&](int bufq, int kh, bf16x8* b) {
    const short* base = &lds[bufq][1][kh][0];
    #pragma unroll
    for (int f = 0; f < 4; ++f) {
      int rr = wn * 64 + f * 16 + l16;
      int g = lhi ^ ((rr >> 1) & 3);
      b[f] = *(const bf16x8*)(base + rr * 32 + g * 8);
    }
  };

  const int nt = K / 64;              // 32 (gemm1) / 64 (gemm2)
  stage(0, 0, 0, 0); stage(0, 1, 0, 0); stage(0, 0, 1, 0); stage(0, 1, 1, 0);
  asm volatile("s_waitcnt vmcnt(4)" ::: "memory");
  __builtin_amdgcn_s_barrier();

  for (int t = 0; t < nt; ++t) {
    const int buf = t & 1, nb = buf ^ 1;
    const int kon = (t + 1) * 64;
    const bool pf = (t + 1 < nt);

    #pragma unroll
    for (int kh = 0; kh < 2; ++kh) {
      if (pf) { stage(nb, 0, kh, kon); stage(nb, 1, kh, kon); }
      bf16x8 a[8], b[4];
      readA(buf, kh, 0, a); readA(buf, kh, 1, a + 4); readB(buf, kh, b);
      __builtin_amdgcn_s_setprio(1);
      #pragma unroll
      for (int mf = 0; mf < 8; ++mf)
        #pragma unroll
        for (int nf = 0; nf < 4; ++nf)
          acc[mf][nf] = __builtin_amdgcn_mfma_f32_16x16x32_bf16(a[mf], b[nf], acc[mf][nf], 0, 0, 0);
      __builtin_amdgcn_s_setprio(0);
      if (pf || kh == 0) {
        if (pf) asm volatile("s_waitcnt vmcnt(4)" ::: "memory");
        else    asm volatile("s_waitcnt vmcnt(0)" ::: "memory");
        __builtin_amdgcn_s_barrier();
      }
    }
  }

  #pragma unroll
  for (int mh = 0; mh < 2; ++mh) {
    #pragma unroll
    for (int f = 0; f < 4; ++f) {
      #pragma unroll
      for (int nf = 0; nf < 4; ++nf) {
        #pragma unroll
        for (int jq = 0; jq < 4; ++jq) {
          int gr = (int)row0 + wm * 128 + mh * 64 + f * 16 + lhi * 4 + jq;
          int gc = col0 + wn * 64 + nf * 16 + l16;
          float v = acc[mh * 4 + f][nf][jq];
          if (MODE == 0) {
            outF[(size_t)gr * N + gc] = v;
          } else {
            if (gc < INTER_)             gate[(size_t)gr * INTER_ + gc] = f2bf(v);
            else if (gc < INTER_ + CDIM) hbc[(size_t)gr * CDIM + (gc - INTER_)] = f2bf(v);
            else if (gc < NPROJ_)        dtraw[(size_t)gr * NHEADS + (gc - INTER_ - CDIM)] = v;
          }
        }
      }
    }
  }
}

// ---------------- depthwise causal conv (K=4) + silu, VECTORIZED (16B/lane) ----------------
__global__ __launch_bounds__(256)
void conv_t(const short* __restrict__ hbc, const float* __restrict__ cw,
            const float* __restrict__ cb, short* __restrict__ xsT,
            short* __restrict__ Bb, short* __restrict__ Cb, short* __restrict__ BbT)
{
  __shared__ short sOut[64][132];
  int ct = blockIdx.y;
  int t = threadIdx.x;
  int cg = (t & 15) * 8;              // channel offset within 128
  int rg = (t >> 4) * 4;              // row offset within 64
  int c0 = ct * 128 + cg;
  int row0 = blockIdx.x * 64;
  int s0 = row0 & (SEQ - 1);

  float w[4][8], bias[8];
  #pragma unroll
  for (int ch = 0; ch < 8; ++ch) {
    f32x4 wv = *(const f32x4*)(cw + (size_t)(c0 + ch) * 4);
    w[0][ch] = wv.x; w[1][ch] = wv.y; w[2][ch] = wv.z; w[3][ch] = wv.w;
    bias[ch] = cb[c0 + ch];
  }
  float in[7][8];
  #pragma unroll
  for (int j = 0; j < 7; ++j) {
    int sp = s0 + rg + j - 3;
    if (sp >= 0) {
      bf16x8 v = *(const bf16x8*)(hbc + (size_t)(row0 + rg + j - 3) * CDIM + c0);
      #pragma unroll
      for (int ch = 0; ch < 8; ++ch) in[j][ch] = bf2f(v[ch]);
    } else {
      #pragma unroll
      for (int ch = 0; ch < 8; ++ch) in[j][ch] = 0.f;
    }
  }
  #pragma unroll
  for (int r = 0; r < 4; ++r) {
    bf16x8 o;
    #pragma unroll
    for (int ch = 0; ch < 8; ++ch) {
      float a = bias[ch] + w[0][ch] * in[r][ch] + w[1][ch] * in[r + 1][ch]
                         + w[2][ch] * in[r + 2][ch] + w[3][ch] * in[r + 3][ch];
      float v = a / (1.f + expf(-a));
      o[ch] = f2bf(v);
    }
    if (ct < 33) {
      *(short4v*)(&sOut[rg + r][cg])     = (short4v){o[0], o[1], o[2], o[3]};
      *(short4v*)(&sOut[rg + r][cg + 4]) = (short4v){o[4], o[5], o[6], o[7]};
    }
    if (ct == 32)      *(bf16x8*)(Bb + (size_t)(row0 + rg + r) * NSTATE + cg) = o;
    else if (ct == 33) *(bf16x8*)(Cb + (size_t)(row0 + rg + r) * NSTATE + cg) = o;
  }
  if (ct >= 33) return;
  __syncthreads();
  int p = t >> 1, sh = (t & 1) * 32;
  int b = row0 >> 12;
  size_t dst;
  short* outp;
  if (ct < 32) { outp = xsT; dst = ((size_t)(b * 32 + ct) * 128 + p) * SEQ + s0 + sh; }
  else         { outp = BbT; dst = ((size_t)b * 128 + p) * SEQ + s0 + sh; }
  #pragma unroll
  for (int g = 0; g < 8; ++g) {
    short4v o;
    o[0] = sOut[sh + g * 4 + 0][p];
    o[1] = sOut[sh + g * 4 + 1][p];
    o[2] = sOut[sh + g * 4 + 2][p];
    o[3] = sOut[sh + g * 4 + 3][p];
    *(short4v*)(outp + dst + g * 4) = o;
  }
}

// ---------------- dt = clip(softplus(dt_raw + bias), 0, 100) -> transposed dtT[h][row] ----
__global__ void dt_proc(const float* __restrict__ dtraw, const float* __restrict__ dtb,
                        float* __restrict__ dtT, int n) {
  int i = blockIdx.x * 256 + threadIdx.x;
  if (i >= n) return;
  float x = dtraw[i] + dtb[i & (NHEADS - 1)];
  float sp = (x > 20.f) ? x : log1pf(expf(x));
  float d = fminf(fmaxf(sp, 0.f), 100.f);
  int row = i >> 5, h = i & 31;
  dtT[(size_t)h * NROWS + row] = d;
}

// ---------------- chunk state (MFMA): S^T[p][n] = sum_l xdt_decay[l][p] * B[l][n], bf16 out ----
__global__ __launch_bounds__(256)
void ssm_state(const short* __restrict__ xsT, const short* __restrict__ BbT,
               const float* __restrict__ dtT, const float* __restrict__ Alog,
               short* __restrict__ csb, float* __restrict__ dAsum)
{
  int blk = blockIdx.x;                       // (b*16+cc)*32+h
  int h = blk & 31, cc = (blk >> 5) & 15, b = blk >> 9;
  int tid = threadIdx.x, lane = tid & 63, wave = tid >> 6;
  int l16 = lane & 15, lhi = lane >> 4;
  int s0 = cc * CHUNK_;

  __shared__ float acum[256];
  __shared__ float sdt[256];
  __shared__ float wsum[4];
  { float Ah = -expf(Alog[h]);
    float d = dtT[(size_t)h * NROWS + (size_t)b * SEQ + s0 + tid];
    sdt[tid] = d;
    float v = Ah * d;
    #pragma unroll
    for (int off = 1; off < 64; off <<= 1) {
      float t = __shfl_up(v, off, 64);
      if (lane >= off) v += t;
    }
    if (lane == 63) wsum[wave] = v;
    __syncthreads();
    float addv = 0.f;
    #pragma unroll
    for (int w = 0; w < 3; ++w) if (w < wave) addv += wsum[w];
    acum[tid] = v + addv;
  }
  __syncthreads();
  float alast = acum[255];

  const short* xbase = xsT + ((size_t)(b * 32 + h) * 128) * SEQ + s0;
  const short* bbase = BbT + ((size_t)b * 128) * SEQ + s0;

  f32x4 acc[2][8];
  #pragma unroll
  for (int m = 0; m < 2; ++m)
    #pragma unroll
    for (int n = 0; n < 8; ++n) acc[m][n] = (f32x4){0.f, 0.f, 0.f, 0.f};

  for (int lt0 = 0; lt0 < 256; lt0 += 32) {
    float fe[8];
    #pragma unroll
    for (int e = 0; e < 8; ++e) {
      int kl = lt0 + lhi * 8 + e;
      fe[e] = sdt[kl] * __expf(alast - acum[kl]);
    }
    bf16x8 af[2];
    #pragma unroll
    for (int m = 0; m < 2; ++m) {
      bf16x8 raw = *(const bf16x8*)(xbase + (size_t)(wave * 32 + m * 16 + l16) * SEQ + lt0 + lhi * 8);
      bf16x8 sc;
      #pragma unroll
      for (int e = 0; e < 8; ++e) sc[e] = f2bf(bf2f(raw[e]) * fe[e]);
      af[m] = sc;
    }
    #pragma unroll
    for (int n = 0; n < 8; ++n) {
      bf16x8 bfv = *(const bf16x8*)(bbase + (size_t)(n * 16 + l16) * SEQ + lt0 + lhi * 8);
      acc[0][n] = __builtin_amdgcn_mfma_f32_16x16x32_bf16(af[0], bfv, acc[0][n], 0, 0, 0);
      acc[1][n] = __builtin_amdgcn_mfma_f32_16x16x32_bf16(af[1], bfv, acc[1][n], 0, 0, 0);
    }
  }
  size_t base = (size_t)blk * 16384;
  #pragma unroll
  for (int m = 0; m < 2; ++m)
    #pragma unroll
    for (int n = 0; n < 8; ++n)
      #pragma unroll
      for (int j = 0; j < 4; ++j) {
        int p = wave * 32 + m * 16 + lhi * 4 + j;
        int ng = n * 16 + l16;
        csb[base + (size_t)p * NSTATE + ng] = f2bf(acc[m][n][j]);
      }
  if (tid == 0) dAsum[blk] = alast;
}

// ---------------- inter-chunk sequential scan (IN-PLACE bf16: chunk-state -> prev-state) ----
__global__ void ssm_scan(short* __restrict__ csb, const float* __restrict__ dAsum) {
  int idx = blockIdx.x * 256 + threadIdx.x;   // over BATCH*HEADS*16384
  int np = idx & 16383;
  int bh = idx >> 14;
  int h = bh & 31, b = bh >> 5;
  float run = 0.f;
  #pragma unroll
  for (int c = 0; c < NCH; ++c) {
    size_t base = ((size_t)((b * NCH + c) * NHEADS + h)) * 16384 + np;
    float v = bf2f(csb[base]);
    csb[base] = f2bf(run);
    run = run * __expf(dAsum[(b * NCH + c) * NHEADS + h]) + v;
  }
}

// ---------------- Y (MFMA): Y = M' @ xdt + exp(acum)*(C @ S_prev^T), gate in-place ----
__global__ __launch_bounds__(256)
void ssm_y(const short* __restrict__ xsT, const short* __restrict__ Bb,
           const short* __restrict__ Cb, const float* __restrict__ dtT,
           const float* __restrict__ Alog, const float* __restrict__ Dv,
           const short* __restrict__ csb, short* __restrict__ gateY)
{
  int blk = blockIdx.y, lt = blockIdx.x;
  int h = blk & 31, cc = (blk >> 5) & 15, b = blk >> 9;
  int tid = threadIdx.x, lane = tid & 63, wave = tid >> 6;
  int l16 = lane & 15, lhi = lane >> 4;
  int s0 = cc * CHUNK_;
  size_t row0 = (size_t)b * SEQ + s0;

  __shared__ float acum[256];
  __shared__ float sdt[256];
  __shared__ float wsum[4];
  __shared__ __align__(16) short M_lds[64 * 264];

  { float Ah = -expf(Alog[h]);
    float d = dtT[(size_t)h * NROWS + row0 + tid];
    sdt[tid] = d;
    float v = Ah * d;
    #pragma unroll
    for (int off = 1; off < 64; off <<= 1) {
      float t = __shfl_up(v, off, 64);
      if (lane >= off) v += t;
    }
    if (lane == 63) wsum[wave] = v;
    __syncthreads();
    float addv = 0.f;
    #pragma unroll
    for (int w = 0; w < 3; ++w) if (w < wave) addv += wsum[w];
    acum[tid] = v + addv;
  }
  __syncthreads();

  float Dh = Dv[h];

  // ---- phase 1: G = C_l · B^T, decay+mask(+D/dt diag) -> M_lds bf16 (wave > lt skipped)
  if (wave <= lt) {
    f32x4 acc1[4][4];
    #pragma unroll
    for (int m = 0; m < 4; ++m)
      #pragma unroll
      for (int n = 0; n < 4; ++n) acc1[m][n] = (f32x4){0.f, 0.f, 0.f, 0.f};
    for (int kk = 0; kk < NSTATE; kk += 32) {
      bf16x8 af[4], bv[4];
      #pragma unroll
      for (int m = 0; m < 4; ++m)
        af[m] = *(const bf16x8*)(Cb + (row0 + lt * 64 + m * 16 + l16) * NSTATE + kk + lhi * 8);
      #pragma unroll
      for (int n = 0; n < 4; ++n)
        bv[n] = *(const bf16x8*)(Bb + (row0 + wave * 64 + n * 16 + l16) * NSTATE + kk + lhi * 8);
      #pragma unroll
      for (int m = 0; m < 4; ++m)
        #pragma unroll
        for (int n = 0; n < 4; ++n)
          acc1[m][n] = __builtin_amdgcn_mfma_f32_16x16x32_bf16(af[m], bv[n], acc1[m][n], 0, 0, 0);
    }
    float as_[4]; int sg_[4];
    #pragma unroll
    for (int n = 0; n < 4; ++n) { sg_[n] = wave * 64 + n * 16 + l16; as_[n] = acum[sg_[n]]; }
    #pragma unroll
    for (int m = 0; m < 4; ++m) {
      #pragma unroll
      for (int j = 0; j < 4; ++j) {
        int ll = m * 16 + lhi * 4 + j;
        int lg = lt * 64 + ll;
        float al = acum[lg];
        float dinv = Dh / fmaxf(sdt[lg], 1e-20f);
        #pragma unroll
        for (int n = 0; n < 4; ++n) {
          float v = 0.f;
          if (sg_[n] <= lg) {
            v = acc1[m][n][j] * __expf(al - as_[n]);
            if (sg_[n] == lg) v += dinv;
          }
          M_lds[ll * 264 + wave * 64 + n * 16 + l16] = f2bf(v);
        }
      }
    }
  }
  __syncthreads();

  const short* xbase = xsT + ((size_t)(b * 32 + h) * 128) * SEQ + s0;

  // ---- phase 2: Y_diag = M' @ xdt  (xdt^T frags direct from xsT global)
  f32x4 accY[4][2];
  #pragma unroll
  for (int m = 0; m < 4; ++m) { accY[m][0] = (f32x4){0,0,0,0}; accY[m][1] = (f32x4){0,0,0,0}; }
  int smax = (lt + 1) * 64;
  for (int st = 0; st < smax; st += 32) {
    float fe[8];
    #pragma unroll
    for (int e = 0; e < 8; ++e) fe[e] = sdt[st + lhi * 8 + e];
    bf16x8 bv2[2];
    #pragma unroll
    for (int n = 0; n < 2; ++n) {
      bf16x8 raw = *(const bf16x8*)(xbase + (size_t)(wave * 32 + n * 16 + l16) * SEQ + st + lhi * 8);
      bf16x8 sc;
      #pragma unroll
      for (int e = 0; e < 8; ++e) sc[e] = f2bf(bf2f(raw[e]) * fe[e]);
      bv2[n] = sc;
    }
    #pragma unroll
    for (int m = 0; m < 4; ++m) {
      bf16x8 a = *(const bf16x8*)(M_lds + (m * 16 + l16) * 264 + st + lhi * 8);
      accY[m][0] = __builtin_amdgcn_mfma_f32_16x16x32_bf16(a, bv2[0], accY[m][0], 0, 0, 0);
      accY[m][1] = __builtin_amdgcn_mfma_f32_16x16x32_bf16(a, bv2[1], accY[m][1], 0, 0, 0);
    }
  }

  // ---- phase 3: Y_off = C @ S_prev^T (bf16 S^T frags direct from global)
  f32x4 accO[4][2];
  #pragma unroll
  for (int m = 0; m < 4; ++m) { accO[m][0] = (f32x4){0,0,0,0}; accO[m][1] = (f32x4){0,0,0,0}; }
  const short* sbase = csb + (size_t)blk * 16384;
  for (int nt = 0; nt < NSTATE; nt += 32) {
    bf16x8 bv2[2];
    #pragma unroll
    for (int n = 0; n < 2; ++n) {
      int p = wave * 32 + n * 16 + l16;
      bv2[n] = *(const bf16x8*)(sbase + (size_t)p * NSTATE + nt + lhi * 8);
    }
    #pragma unroll
    for (int m = 0; m < 4; ++m) {
      bf16x8 a = *(const bf16x8*)(Cb + (row0 + lt * 64 + m * 16 + l16) * NSTATE + nt + lhi * 8);
      accO[m][0] = __builtin_amdgcn_mfma_f32_16x16x32_bf16(a, bv2[0], accO[m][0], 0, 0, 0);
      accO[m][1] = __builtin_amdgcn_mfma_f32_16x16x32_bf16(a, bv2[1], accO[m][1], 0, 0, 0);
    }
  }

  // ---- epilogue: Y = accY + exp(acum[l])*accO; gate in place
  #pragma unroll
  for (int m = 0; m < 4; ++m) {
    #pragma unroll
    for (int j = 0; j < 4; ++j) {
      int ll = m * 16 + lhi * 4 + j;
      float e = __expf(acum[lt * 64 + ll]);
      size_t row = row0 + lt * 64 + ll;
      #pragma unroll
      for (int n = 0; n < 2; ++n) {
        int p = wave * 32 + n * 16 + l16;
        size_t adr = row * INTER_ + h * HDIM + p;
        float yv = accY[m][n][j] + e * accO[m][n][j];
        float g = bf2f(gateY[adr]);
        gateY[adr] = f2bf(yv * g / (1.f + expf(-g)));
      }
    }
  }
}

// ---------------- RMSNorm in-place on bf16 gated y (vectorized 16-elem/thread) ----------------
__global__ __launch_bounds__(256)
void gate_norm(short* __restrict__ ybf, const float* __restrict__ nw)
{
  int row = blockIdx.x;
  int tid = threadIdx.x;
  size_t base = (size_t)row * INTER_ + (size_t)tid * 16;
  bf16x8 v0 = *(const bf16x8*)(ybf + base);
  bf16x8 v1 = *(const bf16x8*)(ybf + base + 8);
  float vals[16];
  float ss = 0.f;
  #pragma unroll
  for (int i = 0; i < 8; ++i) {
    vals[i] = bf2f(v0[i]); vals[8 + i] = bf2f(v1[i]);
  }
  #pragma unroll
  for (int i = 0; i < 16; ++i) ss += vals[i] * vals[i];
  #pragma unroll
  for (int off = 32; off > 0; off >>= 1) ss += __shfl_down(ss, off);
  __shared__ float ws4[4];
  if ((tid & 63) == 0) ws4[tid >> 6] = ss;
  __syncthreads();
  float tot = ws4[0] + ws4[1] + ws4[2] + ws4[3];
  float scale = rsqrtf(tot * (1.f / 4096.f) + 1e-5f);
  bf16x8 o0, o1;
  #pragma unroll
  for (int i = 0; i < 8; ++i) {
    o0[i] = f2bf(vals[i] * scale * nw[tid * 16 + i]);
    o1[i] = f2bf(vals[8 + i] * scale * nw[tid * 16 + 8 + i]);
  }
  *(bf16x8*)(ybf + base) = o0;
  *(bf16x8*)(ybf + base + 8) = o1;
}

// ---------------- launch ----------------
extern "C" void kernel_launch(void* const* d_in, const int* in_sizes, int n_in,
                              void* d_out, int out_size, void* d_ws, size_t ws_size,
                              hipStream_t stream)
{
  const float* Xf   = (const float*)d_in[0];
  const float* W1f  = (const float*)d_in[1];
  const float* cw   = (const float*)d_in[2];
  const float* cb   = (const float*)d_in[3];
  const float* Alog = (const float*)d_in[4];
  const float* dtb  = (const float*)d_in[5];
  const float* Dv   = (const float*)d_in[6];
  const float* nw   = (const float*)d_in[7];
  const float* W2f  = (const float*)d_in[8];
  float* outp = (float*)d_out;
  char* ws = (char*)d_ws;

  // ---- workspace layout: ~232.8 MB (lifetime-aliased), exact r16 ----
  size_t off = 0;
  short* Xb  = (short*)(ws + off); off += (size_t)NROWS * HID * 2;      // 33.55 MB
  short* W1b = (short*)(ws + off); off += (size_t)NPAD * HID * 2;       // 35.65 MB (zero-padded)
  short* xsT = (short*)ws;   // alias over Xb+W1b (dead after gemm1): 67.1 <= 69.2 MB
  short* W2b = (short*)(ws + off); off += (size_t)HID * INTER_ * 2;     // 16.78 MB
  short* gateY = (short*)(ws + off); off += (size_t)NROWS * INTER_ * 2; // 67.11 MB
  short* hbc  = (short*)(ws + off); off += (size_t)NROWS * CDIM * 2;    // 71.30 MB
  float* dtv  = (float*)(ws + off); off += (size_t)NROWS * NHEADS * 4;  // 1.05 MB
  float* dtT  = (float*)(ws + off); off += (size_t)NROWS * NHEADS * 4;  // 1.05 MB
  short* Bb   = (short*)(ws + off); off += (size_t)NROWS * NSTATE * 2;  // 2.10 MB
  short* Cb   = (short*)(ws + off); off += (size_t)NROWS * NSTATE * 2;  // 2.10 MB
  short* BbT  = (short*)(ws + off); off += (size_t)NROWS * NSTATE * 2;  // 2.10 MB
  float* dAs  = (float*)(ws + off); off += 4096;
  short* csb  = (short*)hbc;  // alias over hbc (dead after conv): 33.5 <= 71.3 MB

  cvt_bf16<<<(NROWS * HID / 4 + 255) / 256, 256, 0, stream>>>(
      Xf, Xb, NROWS * HID / 4, NROWS * HID / 4);
  cvt_bf16<<<(NPAD * HID / 4 + 255) / 256, 256, 0, stream>>>(
      W1f, W1b, NPAD * HID / 4, NPROJ_ * HID / 4);
  cvt_bf16<<<(HID * INTER_ / 4 + 255) / 256, 256, 0, stream>>>(
      W2f, W2b, HID * INTER_ / 4, HID * INTER_ / 4);

  // gemm1: 32 row tiles x 34 col tiles; bm fast
  gemm256<1><<<(NROWS / 256) * (NPAD / 256), 512, 0, stream>>>(
      Xb, W1b, NROWS, NPROJ_, HID, NROWS / 256, nullptr, gateY, hbc, dtv);

  dt_proc<<<(NROWS * NHEADS) / 256, 256, 0, stream>>>(dtv, dtb, dtT, NROWS * NHEADS);
  conv_t<<<dim3(NROWS / 64, 34), 256, 0, stream>>>(hbc, cw, cb, xsT, Bb, Cb, BbT);

  ssm_state<<<BATCH * NCH * NHEADS, 256, 0, stream>>>(xsT, BbT, dtT, Alog, csb, dAs);
  ssm_scan<<<(BATCH * NHEADS * 16384) / 256, 256, 0, stream>>>(csb, dAs);
  ssm_y<<<dim3(4, BATCH * NCH * NHEADS), 256, 0, stream>>>(xsT, Bb, Cb, dtT, Alog, Dv, csb, gateY);

  gate_norm<<<NROWS, 256, 0, stream>>>(gateY, nw);

  // gemm2: 32 row tiles x 8 col tiles
  gemm256<0><<<(NROWS / 256) * (HID / 256), 512, 0, stream>>>(
      gateY, W2b, NROWS, HID, INTER_, NROWS / 256, outp, nullptr, nullptr, nullptr);
}